// Round 3
// baseline (421.542 us; speedup 1.0000x reference)
//
#include <hip/hip_runtime.h>

#define FDIM 128
#define HDIM 64
#define MSIZE 64
#define IMG_W 56
#define IMG_H 56
#define NPIX (IMG_W * IMG_H)
#define NB 8
#define NPTS 65536

typedef _Float16 f16x8 __attribute__((ext_vector_type(8)));
typedef float f32x4 __attribute__((ext_vector_type(4)));
typedef int i32x4 __attribute__((ext_vector_type(4)));

// d_ws layout:
//   [0, 32768)     : W1 fragments fp16 (8kt*4nt*64lane*8)
//   [32768, 40960) : W2 fragments
//   [40960, 49152) : W3 fragments
//   [49152, +6.4MB): transposed features (B, H*W, C) fp16
#define W2_OFF 16384   // in halves
#define W3_OFF 20480
#define FT_BYTE_OFF 49152

// wave-local LDS fence: orders this wave's ds ops without the full
// vmcnt(0) drain that s_barrier/__syncthreads forces.
__device__ __forceinline__ void lds_fence() {
    __asm__ volatile("s_waitcnt lgkmcnt(0)" ::: "memory");
}

// ---------------- transpose (B,C,H,W) fp32 -> (B, H*W, C) fp16 ----------------
__global__ __launch_bounds__(256) void transpose_feats16(const float* __restrict__ in,
                                                         _Float16* __restrict__ out) {
    __shared__ float tile[32][33];
    const int pt = blockIdx.x * 32;
    const int ct = blockIdx.y * 32;
    const int b  = blockIdx.z;
    const float* src = in + (size_t)b * FDIM * NPIX;
    _Float16*    dst = out + (size_t)b * NPIX * FDIM;
    const int tx = threadIdx.x, ty = threadIdx.y;
#pragma unroll
    for (int i = 0; i < 32; i += 8)
        tile[ty + i][tx] = src[(size_t)(ct + ty + i) * NPIX + (pt + tx)];
    __syncthreads();
#pragma unroll
    for (int i = 0; i < 32; i += 8)
        dst[(size_t)(pt + ty + i) * FDIM + (ct + tx)] = (_Float16)tile[tx][ty + i];
}

// ---------------- pack W1/W2/W3 into MFMA B-fragment order (fp16) ----------------
// frag element j of lane l for tile (kt,nt): B[k = kt*32 + (l>>4)*8 + j][n = nt*16 + (l&15)]
// W1 k-perm: k<128 -> img channel k; k>=128 -> fd=k-128, row = 128 + (fd&1)*64 + (fd>>1)
// (A-gen emits interleaved (sin_m, cos_m); must match exactly.)
__global__ __launch_bounds__(256) void pack_weights(const float* __restrict__ W1,
                                                    const float* __restrict__ W2,
                                                    const float* __restrict__ W3,
                                                    _Float16* __restrict__ ws) {
    const int t = blockIdx.x * 256 + threadIdx.x;
    if (t >= 3072) return;
    const int l = t & 63;
    const int q = l >> 4;
    const int col = l & 15;
    const int frag = t >> 6;  // 0..47
    if (frag < 32) {
        const int kt = frag >> 2, nt = frag & 3;
#pragma unroll
        for (int j = 0; j < 8; ++j) {
            int k = kt * 32 + q * 8 + j;
            int row = (k < 128) ? k : (128 + (k & 1) * 64 + ((k - 128) >> 1));
            ws[((size_t)(frag * 64 + l)) * 8 + j] = (_Float16)W1[row * HDIM + nt * 16 + col];
        }
    } else if (frag < 40) {
        const int f2 = frag - 32;
        const int kt = f2 >> 2, nt = f2 & 3;
#pragma unroll
        for (int j = 0; j < 8; ++j) {
            int row = kt * 32 + q * 8 + j;
            ws[W2_OFF + ((size_t)(f2 * 64 + l)) * 8 + j] = (_Float16)W2[row * HDIM + nt * 16 + col];
        }
    } else {
        const int f3 = frag - 40;
        const int kt = f3 >> 2, nt = f3 & 3;
#pragma unroll
        for (int j = 0; j < 8; ++j) {
            int row = kt * 32 + q * 8 + j;
            ws[W3_OFF + ((size_t)(f3 * 64 + l)) * 8 + j] = (_Float16)W3[row * HDIM + nt * 16 + col];
        }
    }
}

// ---------------- fused decoder: 4 independent waves/block, 64 pts/wave ----------------
__global__ __launch_bounds__(256, 3) void decoder_mfma2(
    const _Float16* __restrict__ ft,   // (B, HW, C) fp16
    const float* __restrict__ points,
    const float* __restrict__ Kmat, const float* __restrict__ Rt,
    const float* __restrict__ Bg,
    const _Float16* __restrict__ wfrag,
    const float* __restrict__ b1, const float* __restrict__ b2,
    const float* __restrict__ b3,
    const float* __restrict__ W4, const float* __restrict__ b4,
    float* __restrict__ out) {
    // per-wave private 9216B slice; used as share-records in L1, A-tile in L2/L3
    __shared__ _Float16 lds[4 * 64 * 72];
    const int tid = threadIdx.x;
    const int wid = tid >> 6;
    const int l   = tid & 63;
    const int q   = l >> 4;
    const int col = l & 15;
    const int b    = blockIdx.x >> 8;           // 256 blocks per batch
    const int base = blockIdx.x * 256 + wid * 64;
    const int gid  = base + l;
    _Float16* Ah = lds + wid * 64 * 72;
    float* sh = (float*)Ah;
    int*   shi = (int*)Ah;

    // ---- own point: projection + bilinear weights (verified fp32 chain) ----
    const float px = points[(size_t)gid * 3 + 0];
    const float py = points[(size_t)gid * 3 + 1];
    const float pz = points[(size_t)gid * 3 + 2];
    const float* rt = Rt + b * 12;
    const float* km = Kmat + b * 9;
    float cx = rt[0] * px + rt[1] * py + rt[2]  * pz + rt[3];
    float cy = rt[4] * px + rt[5] * py + rt[6]  * pz + rt[7];
    float cz = rt[8] * px + rt[9] * py + rt[10] * pz + rt[11];
    float ix = km[0] * cx + km[1] * cy + km[2] * cz;
    float iy = km[3] * cx + km[4] * cy + km[5] * cz;
    float iz = km[6] * cx + km[7] * cy + km[8] * cz;
    float z  = iz + 1e-8f;
    float u  = ix / z;
    float v  = iy / z;
    float valid = (iz > 0.0f) ? 1.0f : 0.0f;
    float u_norm = (2.0f * u + 1.0f) / (float)IMG_W - 1.0f;
    float v_norm = (2.0f * v + 1.0f) / (float)IMG_H - 1.0f;
    float x = ((u_norm + 1.0f) * (float)IMG_W - 1.0f) * 0.5f;
    float y = ((v_norm + 1.0f) * (float)IMG_H - 1.0f) * 0.5f;
    float x0f = floorf(x), y0f = floorf(y);
    float wx1 = x - x0f, wy1 = y - y0f;
    float wx0 = 1.0f - wx1, wy0 = 1.0f - wy1;
    int x0 = (int)x0f, y0 = (int)y0f;
    int x1 = x0 + 1, y1 = y0 + 1;
    int x0c = x0 < 0 ? 0 : (x0 > IMG_W - 1 ? IMG_W - 1 : x0);
    int x1c = x1 < 0 ? 0 : (x1 > IMG_W - 1 ? IMG_W - 1 : x1);
    int y0c = y0 < 0 ? 0 : (y0 > IMG_H - 1 ? IMG_H - 1 : y0);
    int y1c = y1 < 0 ? 0 : (y1 > IMG_H - 1 ? IMG_H - 1 : y1);
    float mx0 = (x0 >= 0 && x0 < IMG_W) ? 1.0f : 0.0f;
    float mx1 = (x1 >= 0 && x1 < IMG_W) ? 1.0f : 0.0f;
    float my0 = (y0 >= 0 && y0 < IMG_H) ? 1.0f : 0.0f;
    float my1 = (y1 >= 0 && y1 < IMG_H) ? 1.0f : 0.0f;
    const int pb = b * NPIX;
    // share record: 4 weights, 4 corner half-indices, xyz (stride 12 words = 48B)
    sh[l * 12 + 0] = wx0 * wy0 * mx0 * my0 * valid;
    sh[l * 12 + 1] = wx1 * wy0 * mx1 * my0 * valid;
    sh[l * 12 + 2] = wx0 * wy1 * mx0 * my1 * valid;
    sh[l * 12 + 3] = wx1 * wy1 * mx1 * my1 * valid;
    shi[l * 12 + 4] = (pb + y0c * IMG_W + x0c) * FDIM;
    shi[l * 12 + 5] = (pb + y0c * IMG_W + x1c) * FDIM;
    shi[l * 12 + 6] = (pb + y1c * IMG_W + x0c) * FDIM;
    shi[l * 12 + 7] = (pb + y1c * IMG_W + x1c) * FDIM;
    sh[l * 12 + 8]  = px;
    sh[l * 12 + 9]  = py;
    sh[l * 12 + 10] = pz;
    lds_fence();

    const f32x4 zero4 = {0.0f, 0.0f, 0.0f, 0.0f};
    f32x4 acc[4][4];
#pragma unroll
    for (int mt = 0; mt < 4; ++mt)
#pragma unroll
        for (int nt = 0; nt < 4; ++nt) acc[mt][nt] = zero4;

    // ================= layer 1: A-frags generated directly in registers =================
#pragma unroll 1
    for (int mt = 0; mt < 4; ++mt) {
        const float* e = sh + (mt * 16 + col) * 12;
        f32x4 wv = *(const f32x4*)(e);       // w00,w10,w01,w11
        i32x4 iv = *(const i32x4*)(e + 4);   // corner half-indices
        float qx = e[8], qy = e[9], qz = e[10];
        // image channels: k-tiles 0..3
#pragma unroll
        for (int ktg = 0; ktg < 4; ++ktg) {
            const int co = ktg * 32 + q * 8;
            f16x8 v00 = *(const f16x8*)(ft + iv.x + co);
            f16x8 v10 = *(const f16x8*)(ft + iv.y + co);
            f16x8 v01 = *(const f16x8*)(ft + iv.z + co);
            f16x8 v11 = *(const f16x8*)(ft + iv.w + co);
            f16x8 af;
#pragma unroll
            for (int j = 0; j < 8; ++j) {
                float r = wv.x * (float)v00[j] + wv.y * (float)v10[j]
                        + wv.z * (float)v01[j] + wv.w * (float)v11[j];
                af[j] = (_Float16)r;
            }
#pragma unroll
            for (int nt = 0; nt < 4; ++nt) {
                f16x8 bf = *(const f16x8*)(wfrag + ((size_t)((ktg * 4 + nt) * 64 + l)) * 8);
                acc[mt][nt] = __builtin_amdgcn_mfma_f32_16x16x32_f16(af, bf, acc[mt][nt], 0, 0, 0);
            }
        }
        // Fourier: k-tiles 4..7, interleaved (sin_m, cos_m); m = ktf*16 + q*4 + i
#pragma unroll
        for (int ktf = 0; ktf < 4; ++ktf) {
            f16x8 af;
#pragma unroll
            for (int i = 0; i < 4; ++i) {
                const int m = ktf * 16 + q * 4 + i;
                float t = Bg[m * 3 + 0] * qx + Bg[m * 3 + 1] * qy + Bg[m * 3 + 2] * qz;
                float tf = t - floorf(t);
                af[2 * i]     = (_Float16)__builtin_amdgcn_sinf(tf);
                af[2 * i + 1] = (_Float16)__builtin_amdgcn_cosf(tf);
            }
#pragma unroll
            for (int nt = 0; nt < 4; ++nt) {
                f16x8 bf = *(const f16x8*)(wfrag + ((size_t)(((4 + ktf) * 4 + nt) * 64 + l)) * 8);
                acc[mt][nt] = __builtin_amdgcn_mfma_f32_16x16x32_f16(af, bf, acc[mt][nt], 0, 0, 0);
            }
        }
    }

    // ---- L1 epilogue: +b1, relu, store h1 in A-layout fp16 (overwrites share) ----
    float bb[4];
#pragma unroll
    for (int nt = 0; nt < 4; ++nt) bb[nt] = b1[nt * 16 + col];
#pragma unroll
    for (int mt = 0; mt < 4; ++mt)
#pragma unroll
        for (int nt = 0; nt < 4; ++nt)
#pragma unroll
            for (int r = 0; r < 4; ++r) {
                float hv = fmaxf(acc[mt][nt][r] + bb[nt], 0.0f);
                Ah[(mt * 16 + q * 4 + r) * 72 + nt * 16 + col] = (_Float16)hv;
            }
    lds_fence();

    // ================= layer 2 =================
#pragma unroll
    for (int mt = 0; mt < 4; ++mt)
#pragma unroll
        for (int nt = 0; nt < 4; ++nt) acc[mt][nt] = zero4;
#pragma unroll
    for (int ktl = 0; ktl < 2; ++ktl) {
        f16x8 bf[4];
#pragma unroll
        for (int nt = 0; nt < 4; ++nt)
            bf[nt] = *(const f16x8*)(wfrag + W2_OFF + ((size_t)((ktl * 4 + nt) * 64 + l)) * 8);
#pragma unroll
        for (int mt = 0; mt < 4; ++mt) {
            f16x8 af = *(const f16x8*)(&Ah[(mt * 16 + col) * 72 + ktl * 32 + q * 8]);
#pragma unroll
            for (int nt = 0; nt < 4; ++nt)
                acc[mt][nt] = __builtin_amdgcn_mfma_f32_16x16x32_f16(af, bf[nt], acc[mt][nt], 0, 0, 0);
        }
    }
    lds_fence();
#pragma unroll
    for (int nt = 0; nt < 4; ++nt) bb[nt] = b2[nt * 16 + col];
#pragma unroll
    for (int mt = 0; mt < 4; ++mt)
#pragma unroll
        for (int nt = 0; nt < 4; ++nt)
#pragma unroll
            for (int r = 0; r < 4; ++r) {
                float hv = fmaxf(acc[mt][nt][r] + bb[nt], 0.0f);
                Ah[(mt * 16 + q * 4 + r) * 72 + nt * 16 + col] = (_Float16)hv;
            }
    lds_fence();

    // ================= layer 3 =================
#pragma unroll
    for (int mt = 0; mt < 4; ++mt)
#pragma unroll
        for (int nt = 0; nt < 4; ++nt) acc[mt][nt] = zero4;
#pragma unroll
    for (int ktl = 0; ktl < 2; ++ktl) {
        f16x8 bf[4];
#pragma unroll
        for (int nt = 0; nt < 4; ++nt)
            bf[nt] = *(const f16x8*)(wfrag + W3_OFF + ((size_t)((ktl * 4 + nt) * 64 + l)) * 8);
#pragma unroll
        for (int mt = 0; mt < 4; ++mt) {
            f16x8 af = *(const f16x8*)(&Ah[(mt * 16 + col) * 72 + ktl * 32 + q * 8]);
#pragma unroll
            for (int nt = 0; nt < 4; ++nt)
                acc[mt][nt] = __builtin_amdgcn_mfma_f32_16x16x32_f16(af, bf[nt], acc[mt][nt], 0, 0, 0);
        }
    }

    // ================= layer 4: relu + dot(W4) + 16-lane shfl reduction =================
    float b3v[4], w4v[4];
#pragma unroll
    for (int nt = 0; nt < 4; ++nt) {
        b3v[nt] = b3[nt * 16 + col];
        w4v[nt] = W4[nt * 16 + col];
    }
    const float b4v = b4[0];
#pragma unroll
    for (int mt = 0; mt < 4; ++mt)
#pragma unroll
        for (int r = 0; r < 4; ++r) {
            float p = 0.0f;
#pragma unroll
            for (int nt = 0; nt < 4; ++nt)
                p = fmaf(fmaxf(acc[mt][nt][r] + b3v[nt], 0.0f), w4v[nt], p);
            p += __shfl_xor(p, 1);
            p += __shfl_xor(p, 2);
            p += __shfl_xor(p, 4);
            p += __shfl_xor(p, 8);
            if (col == 0) out[base + mt * 16 + q * 4 + r] = p + b4v;
        }
}

// ---------------- fallback: verified R1 pure-VALU kernel ----------------
__global__ __launch_bounds__(64, 2) void decoder_valu(
    const float* __restrict__ feats, const float* __restrict__ points,
    const float* __restrict__ Kmat, const float* __restrict__ Rt,
    const float* __restrict__ Bg,
    const float* __restrict__ W1, const float* __restrict__ b1,
    const float* __restrict__ W2, const float* __restrict__ b2,
    const float* __restrict__ W3, const float* __restrict__ b3,
    const float* __restrict__ W4, const float* __restrict__ b4,
    float* __restrict__ out) {
    __shared__ float hbuf[64 * 65];
    const int tid = threadIdx.x;
    const int b   = blockIdx.x / (NPTS / 64);
    const int gid = blockIdx.x * 64 + tid;
    const float px = points[(size_t)gid * 3 + 0];
    const float py = points[(size_t)gid * 3 + 1];
    const float pz = points[(size_t)gid * 3 + 2];
    const float* rt = Rt + b * 12;
    const float* km = Kmat + b * 9;
    float cx = rt[0] * px + rt[1] * py + rt[2]  * pz + rt[3];
    float cy = rt[4] * px + rt[5] * py + rt[6]  * pz + rt[7];
    float cz = rt[8] * px + rt[9] * py + rt[10] * pz + rt[11];
    float ix = km[0] * cx + km[1] * cy + km[2] * cz;
    float iy = km[3] * cx + km[4] * cy + km[5] * cz;
    float iz = km[6] * cx + km[7] * cy + km[8] * cz;
    float z  = iz + 1e-8f;
    float u  = ix / z, v = iy / z;
    float valid = (iz > 0.0f) ? 1.0f : 0.0f;
    float u_norm = (2.0f * u + 1.0f) / (float)IMG_W - 1.0f;
    float v_norm = (2.0f * v + 1.0f) / (float)IMG_H - 1.0f;
    float x = ((u_norm + 1.0f) * (float)IMG_W - 1.0f) * 0.5f;
    float y = ((v_norm + 1.0f) * (float)IMG_H - 1.0f) * 0.5f;
    float x0f = floorf(x), y0f = floorf(y);
    float wx1 = x - x0f, wy1 = y - y0f;
    float wx0 = 1.0f - wx1, wy0 = 1.0f - wy1;
    int x0 = (int)x0f, y0 = (int)y0f;
    int x1 = x0 + 1, y1 = y0 + 1;
    int x0c = x0 < 0 ? 0 : (x0 > IMG_W - 1 ? IMG_W - 1 : x0);
    int x1c = x1 < 0 ? 0 : (x1 > IMG_W - 1 ? IMG_W - 1 : x1);
    int y0c = y0 < 0 ? 0 : (y0 > IMG_H - 1 ? IMG_H - 1 : y0);
    int y1c = y1 < 0 ? 0 : (y1 > IMG_H - 1 ? IMG_H - 1 : y1);
    float mx0 = (x0 >= 0 && x0 < IMG_W) ? 1.0f : 0.0f;
    float mx1 = (x1 >= 0 && x1 < IMG_W) ? 1.0f : 0.0f;
    float my0 = (y0 >= 0 && y0 < IMG_H) ? 1.0f : 0.0f;
    float my1 = (y1 >= 0 && y1 < IMG_H) ? 1.0f : 0.0f;
    float w00 = wx0 * wy0 * mx0 * my0 * valid;
    float w10 = wx1 * wy0 * mx1 * my0 * valid;
    float w01 = wx0 * wy1 * mx0 * my1 * valid;
    float w11 = wx1 * wy1 * mx1 * my1 * valid;
    float h[HDIM];
#pragma unroll
    for (int j = 0; j < HDIM; ++j) h[j] = b1[j];
    const float* fb = feats + (size_t)b * FDIM * NPIX;
    const int p00 = y0c * IMG_W + x0c, p10 = y0c * IMG_W + x1c;
    const int p01 = y1c * IMG_W + x0c, p11 = y1c * IMG_W + x1c;
#pragma unroll 1
    for (int c = 0; c < FDIM; ++c) {
        const float* fp = fb + (size_t)c * NPIX;
        float fv = w00 * fp[p00] + w10 * fp[p10] + w01 * fp[p01] + w11 * fp[p11];
        const float* wr = W1 + (size_t)c * HDIM;
#pragma unroll
        for (int j = 0; j < HDIM; ++j) h[j] = fmaf(fv, wr[j], h[j]);
    }
#pragma unroll 1
    for (int m = 0; m < MSIZE; ++m) {
        float t = Bg[m * 3 + 0] * px + Bg[m * 3 + 1] * py + Bg[m * 3 + 2] * pz;
        float tf = t - floorf(t);
        float s = __builtin_amdgcn_sinf(tf);
        float c = __builtin_amdgcn_cosf(tf);
        const float* wsn = W1 + (size_t)(FDIM + m) * HDIM;
        const float* wcs = W1 + (size_t)(FDIM + MSIZE + m) * HDIM;
#pragma unroll
        for (int j = 0; j < HDIM; ++j)
            h[j] = fmaf(s, wsn[j], fmaf(c, wcs[j], h[j]));
    }
    float* myh = &hbuf[tid * 65];
#pragma unroll
    for (int j = 0; j < HDIM; ++j) myh[j] = fmaxf(h[j], 0.0f);
    float h2[HDIM];
#pragma unroll
    for (int j = 0; j < HDIM; ++j) h2[j] = b2[j];
#pragma unroll 1
    for (int i = 0; i < HDIM; ++i) {
        float hi = myh[i];
        const float* wr = W2 + (size_t)i * HDIM;
#pragma unroll
        for (int j = 0; j < HDIM; ++j) h2[j] = fmaf(hi, wr[j], h2[j]);
    }
#pragma unroll
    for (int j = 0; j < HDIM; ++j) myh[j] = fmaxf(h2[j], 0.0f);
#pragma unroll
    for (int j = 0; j < HDIM; ++j) h[j] = b3[j];
#pragma unroll 1
    for (int i = 0; i < HDIM; ++i) {
        float hi = myh[i];
        const float* wr = W3 + (size_t)i * HDIM;
#pragma unroll
        for (int j = 0; j < HDIM; ++j) h[j] = fmaf(hi, wr[j], h[j]);
    }
    float acc = b4[0];
#pragma unroll
    for (int j = 0; j < HDIM; ++j) acc = fmaf(fmaxf(h[j], 0.0f), W4[j], acc);
    out[gid] = acc;
}

extern "C" void kernel_launch(void* const* d_in, const int* in_sizes, int n_in,
                              void* d_out, int out_size, void* d_ws, size_t ws_size,
                              hipStream_t stream) {
    const float* feats = (const float*)d_in[0];
    const float* pts   = (const float*)d_in[1];
    const float* k     = (const float*)d_in[2];
    const float* rt    = (const float*)d_in[3];
    const float* Bg    = (const float*)d_in[4];
    const float* W1    = (const float*)d_in[5];
    const float* b1    = (const float*)d_in[6];
    const float* W2    = (const float*)d_in[7];
    const float* b2    = (const float*)d_in[8];
    const float* W3    = (const float*)d_in[9];
    const float* b3    = (const float*)d_in[10];
    const float* W4    = (const float*)d_in[11];
    const float* b4    = (const float*)d_in[12];
    float* out = (float*)d_out;

    const size_t ftBytes = (size_t)NB * NPIX * FDIM * sizeof(_Float16);

    if (ws_size >= FT_BYTE_OFF + ftBytes) {
        _Float16* wf = (_Float16*)d_ws;
        _Float16* ft = (_Float16*)((char*)d_ws + FT_BYTE_OFF);
        pack_weights<<<12, 256, 0, stream>>>(W1, W2, W3, wf);
        transpose_feats16<<<dim3(NPIX / 32, FDIM / 32, NB), dim3(32, 8), 0, stream>>>(feats, ft);
        decoder_mfma2<<<NB * NPTS / 256, 256, 0, stream>>>(ft, pts, k, rt, Bg, wf,
                                                           b1, b2, b3, W4, b4, out);
    } else {
        decoder_valu<<<NB * NPTS / 64, 64, 0, stream>>>(feats, pts, k, rt, Bg,
                                                        W1, b1, W2, b2, W3, b3, W4, b4, out);
    }
}

// Round 4
// 186.630 us; speedup vs baseline: 2.2587x; 2.2587x over previous
//
#include <hip/hip_runtime.h>

#define FDIM 128
#define HDIM 64
#define MSIZE 64
#define IMG_W 56
#define IMG_H 56
#define NPIX (IMG_W * IMG_H)
#define NB 8
#define NPTS 65536

typedef _Float16 f16x8 __attribute__((ext_vector_type(8)));
typedef float f32x4 __attribute__((ext_vector_type(4)));
typedef int i32x4 __attribute__((ext_vector_type(4)));

// d_ws layout:
//   [0, 32768)     : W1 fragments fp16 (8kt*4nt*64lane*8)
//   [32768, 40960) : W2 fragments
//   [40960, 49152) : W3 fragments
//   [49152, +6.4MB): transposed features (B, H*W, C) fp16
#define W2_OFF 16384   // in halves
#define W3_OFF 20480
#define FT_BYTE_OFF 49152

// wave-local LDS fence: orders this wave's ds ops without the full
// vmcnt(0) drain that s_barrier/__syncthreads forces.
__device__ __forceinline__ void lds_fence() {
    __asm__ volatile("s_waitcnt lgkmcnt(0)" ::: "memory");
}

// ---- transpose (B,C,H,W) fp32 -> (B,HW,C) fp16; 64px x 128ch tiles ----
// read: 256B contiguous per wave-instr; write: 1KB contiguous per wave-instr.
__global__ __launch_bounds__(256) void transpose_feats16(const float* __restrict__ in,
                                                         _Float16* __restrict__ out) {
    __shared__ float tile[64][129];  // stride 129 -> read-phase banks (tx+c)%32, 2-way free
    const int b = blockIdx.y;
    const int pbase = blockIdx.x * 64;  // 3136 = 49*64, exact
    const int t = threadIdx.x;
    const float* src = in + (size_t)b * FDIM * NPIX;
    _Float16*    dst = out + (size_t)b * NPIX * FDIM;
    const int tx = t & 63;   // pixel within tile
    const int cg = t >> 6;   // channel group 0..3
#pragma unroll
    for (int i = 0; i < 32; ++i) {
        int c = cg * 32 + i;
        tile[tx][c] = src[(size_t)c * NPIX + pbase + tx];
    }
    __syncthreads();
    // write: per g, wave covers 4 rows x 256B = contiguous 1KB
    const int sub = t >> 4;        // 0..15 -> row subindex within g
    const int hk  = (t & 15) * 8;  // halves chunk
#pragma unroll
    for (int g = 0; g < 4; ++g) {
        const int px = g * 16 + sub;
        f16x8 hv;
#pragma unroll
        for (int j = 0; j < 8; ++j) hv[j] = (_Float16)tile[px][hk + j];
        *(f16x8*)(dst + (size_t)(pbase + px) * FDIM + hk) = hv;
    }
}

// ---------------- pack W1/W2/W3 into MFMA B-fragment order (fp16) ----------------
// frag element j of lane l for tile (kt,nt): B[k = kt*32 + (l>>4)*8 + j][n = nt*16 + (l&15)]
// W1 k-perm: k<128 -> img channel k; k>=128 -> fd=k-128, row = 128 + (fd&1)*64 + (fd>>1)
// (A-gen emits interleaved (sin_m, cos_m); must match exactly.)
__global__ __launch_bounds__(256) void pack_weights(const float* __restrict__ W1,
                                                    const float* __restrict__ W2,
                                                    const float* __restrict__ W3,
                                                    _Float16* __restrict__ ws) {
    const int t = blockIdx.x * 256 + threadIdx.x;
    if (t >= 3072) return;
    const int l = t & 63;
    const int q = l >> 4;
    const int col = l & 15;
    const int frag = t >> 6;  // 0..47
    if (frag < 32) {
        const int kt = frag >> 2, nt = frag & 3;
#pragma unroll
        for (int j = 0; j < 8; ++j) {
            int k = kt * 32 + q * 8 + j;
            int row = (k < 128) ? k : (128 + (k & 1) * 64 + ((k - 128) >> 1));
            ws[((size_t)(frag * 64 + l)) * 8 + j] = (_Float16)W1[row * HDIM + nt * 16 + col];
        }
    } else if (frag < 40) {
        const int f2 = frag - 32;
        const int kt = f2 >> 2, nt = f2 & 3;
#pragma unroll
        for (int j = 0; j < 8; ++j) {
            int row = kt * 32 + q * 8 + j;
            ws[W2_OFF + ((size_t)(f2 * 64 + l)) * 8 + j] = (_Float16)W2[row * HDIM + nt * 16 + col];
        }
    } else {
        const int f3 = frag - 40;
        const int kt = f3 >> 2, nt = f3 & 3;
#pragma unroll
        for (int j = 0; j < 8; ++j) {
            int row = kt * 32 + q * 8 + j;
            ws[W3_OFF + ((size_t)(f3 * 64 + l)) * 8 + j] = (_Float16)W3[row * HDIM + nt * 16 + col];
        }
    }
}

// ---------------- fused decoder: 4 independent waves/block, 64 pts/wave ----------------
// (256,2): no VGPR-cap spill pressure; occupancy rises on its own if alloc is small.
__global__ __launch_bounds__(256, 2) void decoder_mfma2(
    const _Float16* __restrict__ ft,   // (B, HW, C) fp16
    const float* __restrict__ points,
    const float* __restrict__ Kmat, const float* __restrict__ Rt,
    const float* __restrict__ Bg,
    const _Float16* __restrict__ wfrag,
    const float* __restrict__ b1, const float* __restrict__ b2,
    const float* __restrict__ b3,
    const float* __restrict__ W4, const float* __restrict__ b4,
    float* __restrict__ out) {
    __shared__ _Float16 lds[4 * 64 * 72];
    const int tid = threadIdx.x;
    const int wid = tid >> 6;
    const int l   = tid & 63;
    const int q   = l >> 4;
    const int col = l & 15;
    const int b    = blockIdx.x >> 8;           // 256 blocks per batch
    const int base = blockIdx.x * 256 + wid * 64;
    const int gid  = base + l;
    _Float16* Ah = lds + wid * 64 * 72;
    float* sh = (float*)Ah;
    int*   shi = (int*)Ah;

    // ---- own point: projection + bilinear weights (verified fp32 chain) ----
    const float px = points[(size_t)gid * 3 + 0];
    const float py = points[(size_t)gid * 3 + 1];
    const float pz = points[(size_t)gid * 3 + 2];
    const float* rt = Rt + b * 12;
    const float* km = Kmat + b * 9;
    float cx = rt[0] * px + rt[1] * py + rt[2]  * pz + rt[3];
    float cy = rt[4] * px + rt[5] * py + rt[6]  * pz + rt[7];
    float cz = rt[8] * px + rt[9] * py + rt[10] * pz + rt[11];
    float ix = km[0] * cx + km[1] * cy + km[2] * cz;
    float iy = km[3] * cx + km[4] * cy + km[5] * cz;
    float iz = km[6] * cx + km[7] * cy + km[8] * cz;
    float z  = iz + 1e-8f;
    float u  = ix / z;
    float v  = iy / z;
    float valid = (iz > 0.0f) ? 1.0f : 0.0f;
    float u_norm = (2.0f * u + 1.0f) / (float)IMG_W - 1.0f;
    float v_norm = (2.0f * v + 1.0f) / (float)IMG_H - 1.0f;
    float x = ((u_norm + 1.0f) * (float)IMG_W - 1.0f) * 0.5f;
    float y = ((v_norm + 1.0f) * (float)IMG_H - 1.0f) * 0.5f;
    float x0f = floorf(x), y0f = floorf(y);
    float wx1 = x - x0f, wy1 = y - y0f;
    float wx0 = 1.0f - wx1, wy0 = 1.0f - wy1;
    int x0 = (int)x0f, y0 = (int)y0f;
    int x1 = x0 + 1, y1 = y0 + 1;
    int x0c = x0 < 0 ? 0 : (x0 > IMG_W - 1 ? IMG_W - 1 : x0);
    int x1c = x1 < 0 ? 0 : (x1 > IMG_W - 1 ? IMG_W - 1 : x1);
    int y0c = y0 < 0 ? 0 : (y0 > IMG_H - 1 ? IMG_H - 1 : y0);
    int y1c = y1 < 0 ? 0 : (y1 > IMG_H - 1 ? IMG_H - 1 : y1);
    float mx0 = (x0 >= 0 && x0 < IMG_W) ? 1.0f : 0.0f;
    float mx1 = (x1 >= 0 && x1 < IMG_W) ? 1.0f : 0.0f;
    float my0 = (y0 >= 0 && y0 < IMG_H) ? 1.0f : 0.0f;
    float my1 = (y1 >= 0 && y1 < IMG_H) ? 1.0f : 0.0f;
    const int pb = b * NPIX;
    sh[l * 12 + 0] = wx0 * wy0 * mx0 * my0 * valid;
    sh[l * 12 + 1] = wx1 * wy0 * mx1 * my0 * valid;
    sh[l * 12 + 2] = wx0 * wy1 * mx0 * my1 * valid;
    sh[l * 12 + 3] = wx1 * wy1 * mx1 * my1 * valid;
    shi[l * 12 + 4] = (pb + y0c * IMG_W + x0c) * FDIM;
    shi[l * 12 + 5] = (pb + y0c * IMG_W + x1c) * FDIM;
    shi[l * 12 + 6] = (pb + y1c * IMG_W + x0c) * FDIM;
    shi[l * 12 + 7] = (pb + y1c * IMG_W + x1c) * FDIM;
    sh[l * 12 + 8]  = px;
    sh[l * 12 + 9]  = py;
    sh[l * 12 + 10] = pz;
    lds_fence();

    const f32x4 zero4 = {0.0f, 0.0f, 0.0f, 0.0f};
    f32x4 acc[4][4];
#pragma unroll
    for (int mt = 0; mt < 4; ++mt)
#pragma unroll
        for (int nt = 0; nt < 4; ++nt) acc[mt][nt] = zero4;

    // ====== layer 1: A-frags in registers. mt FULLY UNROLLED (static acc idx!) ======
#pragma unroll
    for (int mt = 0; mt < 4; ++mt) {
        const float* e = sh + (mt * 16 + col) * 12;
        f32x4 wv = *(const f32x4*)(e);       // w00,w10,w01,w11
        i32x4 iv = *(const i32x4*)(e + 4);   // corner half-indices
        float qx = e[8], qy = e[9], qz = e[10];
#pragma unroll
        for (int ktg = 0; ktg < 4; ++ktg) {
            const int co = ktg * 32 + q * 8;
            f16x8 v00 = *(const f16x8*)(ft + iv.x + co);
            f16x8 v10 = *(const f16x8*)(ft + iv.y + co);
            f16x8 v01 = *(const f16x8*)(ft + iv.z + co);
            f16x8 v11 = *(const f16x8*)(ft + iv.w + co);
            f16x8 af;
#pragma unroll
            for (int j = 0; j < 8; ++j) {
                float r = wv.x * (float)v00[j] + wv.y * (float)v10[j]
                        + wv.z * (float)v01[j] + wv.w * (float)v11[j];
                af[j] = (_Float16)r;
            }
#pragma unroll
            for (int nt = 0; nt < 4; ++nt) {
                f16x8 bf = *(const f16x8*)(wfrag + ((size_t)((ktg * 4 + nt) * 64 + l)) * 8);
                acc[mt][nt] = __builtin_amdgcn_mfma_f32_16x16x32_f16(af, bf, acc[mt][nt], 0, 0, 0);
            }
        }
#pragma unroll
        for (int ktf = 0; ktf < 4; ++ktf) {
            f16x8 af;
#pragma unroll
            for (int i = 0; i < 4; ++i) {
                const int m = ktf * 16 + q * 4 + i;
                float t = Bg[m * 3 + 0] * qx + Bg[m * 3 + 1] * qy + Bg[m * 3 + 2] * qz;
                float tf = t - floorf(t);
                af[2 * i]     = (_Float16)__builtin_amdgcn_sinf(tf);
                af[2 * i + 1] = (_Float16)__builtin_amdgcn_cosf(tf);
            }
#pragma unroll
            for (int nt = 0; nt < 4; ++nt) {
                f16x8 bf = *(const f16x8*)(wfrag + ((size_t)(((4 + ktf) * 4 + nt) * 64 + l)) * 8);
                acc[mt][nt] = __builtin_amdgcn_mfma_f32_16x16x32_f16(af, bf, acc[mt][nt], 0, 0, 0);
            }
        }
    }

    // ---- L1 epilogue: +b1, relu, store h1 in A-layout fp16 (overwrites share) ----
    float bb[4];
#pragma unroll
    for (int nt = 0; nt < 4; ++nt) bb[nt] = b1[nt * 16 + col];
#pragma unroll
    for (int mt = 0; mt < 4; ++mt)
#pragma unroll
        for (int nt = 0; nt < 4; ++nt)
#pragma unroll
            for (int r = 0; r < 4; ++r) {
                float hv = fmaxf(acc[mt][nt][r] + bb[nt], 0.0f);
                Ah[(mt * 16 + q * 4 + r) * 72 + nt * 16 + col] = (_Float16)hv;
            }
    lds_fence();

    // ================= layer 2 =================
#pragma unroll
    for (int mt = 0; mt < 4; ++mt)
#pragma unroll
        for (int nt = 0; nt < 4; ++nt) acc[mt][nt] = zero4;
#pragma unroll
    for (int ktl = 0; ktl < 2; ++ktl) {
        f16x8 bf[4];
#pragma unroll
        for (int nt = 0; nt < 4; ++nt)
            bf[nt] = *(const f16x8*)(wfrag + W2_OFF + ((size_t)((ktl * 4 + nt) * 64 + l)) * 8);
#pragma unroll
        for (int mt = 0; mt < 4; ++mt) {
            f16x8 af = *(const f16x8*)(&Ah[(mt * 16 + col) * 72 + ktl * 32 + q * 8]);
#pragma unroll
            for (int nt = 0; nt < 4; ++nt)
                acc[mt][nt] = __builtin_amdgcn_mfma_f32_16x16x32_f16(af, bf[nt], acc[mt][nt], 0, 0, 0);
        }
    }
    lds_fence();
#pragma unroll
    for (int nt = 0; nt < 4; ++nt) bb[nt] = b2[nt * 16 + col];
#pragma unroll
    for (int mt = 0; mt < 4; ++mt)
#pragma unroll
        for (int nt = 0; nt < 4; ++nt)
#pragma unroll
            for (int r = 0; r < 4; ++r) {
                float hv = fmaxf(acc[mt][nt][r] + bb[nt], 0.0f);
                Ah[(mt * 16 + q * 4 + r) * 72 + nt * 16 + col] = (_Float16)hv;
            }
    lds_fence();

    // ================= layer 3 =================
#pragma unroll
    for (int mt = 0; mt < 4; ++mt)
#pragma unroll
        for (int nt = 0; nt < 4; ++nt) acc[mt][nt] = zero4;
#pragma unroll
    for (int ktl = 0; ktl < 2; ++ktl) {
        f16x8 bf[4];
#pragma unroll
        for (int nt = 0; nt < 4; ++nt)
            bf[nt] = *(const f16x8*)(wfrag + W3_OFF + ((size_t)((ktl * 4 + nt) * 64 + l)) * 8);
#pragma unroll
        for (int mt = 0; mt < 4; ++mt) {
            f16x8 af = *(const f16x8*)(&Ah[(mt * 16 + col) * 72 + ktl * 32 + q * 8]);
#pragma unroll
            for (int nt = 0; nt < 4; ++nt)
                acc[mt][nt] = __builtin_amdgcn_mfma_f32_16x16x32_f16(af, bf[nt], acc[mt][nt], 0, 0, 0);
        }
    }

    // ================= layer 4: relu + dot(W4) + 16-lane shfl reduction =================
    float b3v[4], w4v[4];
#pragma unroll
    for (int nt = 0; nt < 4; ++nt) {
        b3v[nt] = b3[nt * 16 + col];
        w4v[nt] = W4[nt * 16 + col];
    }
    const float b4v = b4[0];
#pragma unroll
    for (int mt = 0; mt < 4; ++mt)
#pragma unroll
        for (int r = 0; r < 4; ++r) {
            float p = 0.0f;
#pragma unroll
            for (int nt = 0; nt < 4; ++nt)
                p = fmaf(fmaxf(acc[mt][nt][r] + b3v[nt], 0.0f), w4v[nt], p);
            p += __shfl_xor(p, 1);
            p += __shfl_xor(p, 2);
            p += __shfl_xor(p, 4);
            p += __shfl_xor(p, 8);
            if (col == 0) out[base + mt * 16 + q * 4 + r] = p + b4v;
        }
}

// ---------------- fallback: verified R1 pure-VALU kernel ----------------
__global__ __launch_bounds__(64, 2) void decoder_valu(
    const float* __restrict__ feats, const float* __restrict__ points,
    const float* __restrict__ Kmat, const float* __restrict__ Rt,
    const float* __restrict__ Bg,
    const float* __restrict__ W1, const float* __restrict__ b1,
    const float* __restrict__ W2, const float* __restrict__ b2,
    const float* __restrict__ W3, const float* __restrict__ b3,
    const float* __restrict__ W4, const float* __restrict__ b4,
    float* __restrict__ out) {
    __shared__ float hbuf[64 * 65];
    const int tid = threadIdx.x;
    const int b   = blockIdx.x / (NPTS / 64);
    const int gid = blockIdx.x * 64 + tid;
    const float px = points[(size_t)gid * 3 + 0];
    const float py = points[(size_t)gid * 3 + 1];
    const float pz = points[(size_t)gid * 3 + 2];
    const float* rt = Rt + b * 12;
    const float* km = Kmat + b * 9;
    float cx = rt[0] * px + rt[1] * py + rt[2]  * pz + rt[3];
    float cy = rt[4] * px + rt[5] * py + rt[6]  * pz + rt[7];
    float cz = rt[8] * px + rt[9] * py + rt[10] * pz + rt[11];
    float ix = km[0] * cx + km[1] * cy + km[2] * cz;
    float iy = km[3] * cx + km[4] * cy + km[5] * cz;
    float iz = km[6] * cx + km[7] * cy + km[8] * cz;
    float z  = iz + 1e-8f;
    float u  = ix / z, v = iy / z;
    float valid = (iz > 0.0f) ? 1.0f : 0.0f;
    float u_norm = (2.0f * u + 1.0f) / (float)IMG_W - 1.0f;
    float v_norm = (2.0f * v + 1.0f) / (float)IMG_H - 1.0f;
    float x = ((u_norm + 1.0f) * (float)IMG_W - 1.0f) * 0.5f;
    float y = ((v_norm + 1.0f) * (float)IMG_H - 1.0f) * 0.5f;
    float x0f = floorf(x), y0f = floorf(y);
    float wx1 = x - x0f, wy1 = y - y0f;
    float wx0 = 1.0f - wx1, wy0 = 1.0f - wy1;
    int x0 = (int)x0f, y0 = (int)y0f;
    int x1 = x0 + 1, y1 = y0 + 1;
    int x0c = x0 < 0 ? 0 : (x0 > IMG_W - 1 ? IMG_W - 1 : x0);
    int x1c = x1 < 0 ? 0 : (x1 > IMG_W - 1 ? IMG_W - 1 : x1);
    int y0c = y0 < 0 ? 0 : (y0 > IMG_H - 1 ? IMG_H - 1 : y0);
    int y1c = y1 < 0 ? 0 : (y1 > IMG_H - 1 ? IMG_H - 1 : y1);
    float mx0 = (x0 >= 0 && x0 < IMG_W) ? 1.0f : 0.0f;
    float mx1 = (x1 >= 0 && x1 < IMG_W) ? 1.0f : 0.0f;
    float my0 = (y0 >= 0 && y0 < IMG_H) ? 1.0f : 0.0f;
    float my1 = (y1 >= 0 && y1 < IMG_H) ? 1.0f : 0.0f;
    float w00 = wx0 * wy0 * mx0 * my0 * valid;
    float w10 = wx1 * wy0 * mx1 * my0 * valid;
    float w01 = wx0 * wy1 * mx0 * my1 * valid;
    float w11 = wx1 * wy1 * mx1 * my1 * valid;
    float h[HDIM];
#pragma unroll
    for (int j = 0; j < HDIM; ++j) h[j] = b1[j];
    const float* fb = feats + (size_t)b * FDIM * NPIX;
    const int p00 = y0c * IMG_W + x0c, p10 = y0c * IMG_W + x1c;
    const int p01 = y1c * IMG_W + x0c, p11 = y1c * IMG_W + x1c;
#pragma unroll 1
    for (int c = 0; c < FDIM; ++c) {
        const float* fp = fb + (size_t)c * NPIX;
        float fv = w00 * fp[p00] + w10 * fp[p10] + w01 * fp[p01] + w11 * fp[p11];
        const float* wr = W1 + (size_t)c * HDIM;
#pragma unroll
        for (int j = 0; j < HDIM; ++j) h[j] = fmaf(fv, wr[j], h[j]);
    }
#pragma unroll 1
    for (int m = 0; m < MSIZE; ++m) {
        float t = Bg[m * 3 + 0] * px + Bg[m * 3 + 1] * py + Bg[m * 3 + 2] * pz;
        float tf = t - floorf(t);
        float s = __builtin_amdgcn_sinf(tf);
        float c = __builtin_amdgcn_cosf(tf);
        const float* wsn = W1 + (size_t)(FDIM + m) * HDIM;
        const float* wcs = W1 + (size_t)(FDIM + MSIZE + m) * HDIM;
#pragma unroll
        for (int j = 0; j < HDIM; ++j)
            h[j] = fmaf(s, wsn[j], fmaf(c, wcs[j], h[j]));
    }
    float* myh = &hbuf[tid * 65];
#pragma unroll
    for (int j = 0; j < HDIM; ++j) myh[j] = fmaxf(h[j], 0.0f);
    float h2[HDIM];
#pragma unroll
    for (int j = 0; j < HDIM; ++j) h2[j] = b2[j];
#pragma unroll 1
    for (int i = 0; i < HDIM; ++i) {
        float hi = myh[i];
        const float* wr = W2 + (size_t)i * HDIM;
#pragma unroll
        for (int j = 0; j < HDIM; ++j) h2[j] = fmaf(hi, wr[j], h2[j]);
    }
#pragma unroll
    for (int j = 0; j < HDIM; ++j) myh[j] = fmaxf(h2[j], 0.0f);
#pragma unroll
    for (int j = 0; j < HDIM; ++j) h[j] = b3[j];
#pragma unroll 1
    for (int i = 0; i < HDIM; ++i) {
        float hi = myh[i];
        const float* wr = W3 + (size_t)i * HDIM;
#pragma unroll
        for (int j = 0; j < HDIM; ++j) h[j] = fmaf(hi, wr[j], h[j]);
    }
    float acc = b4[0];
#pragma unroll
    for (int j = 0; j < HDIM; ++j) acc = fmaf(fmaxf(h[j], 0.0f), W4[j], acc);
    out[gid] = acc;
}

extern "C" void kernel_launch(void* const* d_in, const int* in_sizes, int n_in,
                              void* d_out, int out_size, void* d_ws, size_t ws_size,
                              hipStream_t stream) {
    const float* feats = (const float*)d_in[0];
    const float* pts   = (const float*)d_in[1];
    const float* k     = (const float*)d_in[2];
    const float* rt    = (const float*)d_in[3];
    const float* Bg    = (const float*)d_in[4];
    const float* W1    = (const float*)d_in[5];
    const float* b1    = (const float*)d_in[6];
    const float* W2    = (const float*)d_in[7];
    const float* b2    = (const float*)d_in[8];
    const float* W3    = (const float*)d_in[9];
    const float* b3    = (const float*)d_in[10];
    const float* W4    = (const float*)d_in[11];
    const float* b4    = (const float*)d_in[12];
    float* out = (float*)d_out;

    const size_t ftBytes = (size_t)NB * NPIX * FDIM * sizeof(_Float16);

    if (ws_size >= FT_BYTE_OFF + ftBytes) {
        _Float16* wf = (_Float16*)d_ws;
        _Float16* ft = (_Float16*)((char*)d_ws + FT_BYTE_OFF);
        pack_weights<<<12, 256, 0, stream>>>(W1, W2, W3, wf);
        transpose_feats16<<<dim3(NPIX / 64, NB), 256, 0, stream>>>(feats, ft);
        decoder_mfma2<<<NB * NPTS / 256, 256, 0, stream>>>(ft, pts, k, rt, Bg, wf,
                                                           b1, b2, b3, W4, b4, out);
    } else {
        decoder_valu<<<NB * NPTS / 64, 64, 0, stream>>>(feats, pts, k, rt, Bg,
                                                        W1, b1, W2, b2, W3, b3, W4, b4, out);
    }
}

// Round 5
// 184.128 us; speedup vs baseline: 2.2894x; 1.0136x over previous
//
#include <hip/hip_runtime.h>

#define FDIM 128
#define HDIM 64
#define MSIZE 64
#define IMG_W 56
#define IMG_H 56
#define NPIX (IMG_W * IMG_H)
#define NB 8
#define NPTS 65536

typedef _Float16 f16x8 __attribute__((ext_vector_type(8)));
typedef float f32x4 __attribute__((ext_vector_type(4)));
typedef int i32x4 __attribute__((ext_vector_type(4)));

// d_ws layout:
//   [0, 32768)     : W1 fragments fp16 (8kt*4nt*64lane*8)
//   [32768, 40960) : W2 fragments
//   [40960, 49152) : W3 fragments
//   [49152, +6.4MB): transposed features (B, H*W, C) fp16
#define W2_OFF 16384   // in halves
#define W3_OFF 20480
#define FT_BYTE_OFF 49152
#define TR_BLOCKS (NPIX / 64 * NB)   // 392

// wave-local LDS fence: orders this wave's ds ops without the full
// vmcnt(0)+barrier drain __syncthreads forces.
__device__ __forceinline__ void lds_fence() {
    __asm__ volatile("s_waitcnt lgkmcnt(0)" ::: "memory");
}

// ---- fused prep: blocks [0,392) transpose feats fp32->fp16 (B,HW,C);
//      blocks [392,404) pack W1/W2/W3 into MFMA B-fragment order ----
// frag element j of lane l for tile (kt,nt): B[k = kt*32 + (l>>4)*8 + j][n = nt*16 + (l&15)]
// W1 k-perm: k<128 -> img channel k; k>=128 -> row = 128 + (k&1)*64 + ((k-128)>>1)
// (decoder emits interleaved (sin_m, cos_m); must match exactly.)
__global__ __launch_bounds__(256) void prep_kernel(const float* __restrict__ in,
                                                   const float* __restrict__ W1,
                                                   const float* __restrict__ W2,
                                                   const float* __restrict__ W3,
                                                   _Float16* __restrict__ ws) {
    if (blockIdx.x < TR_BLOCKS) {
        // ---------- transpose: 64px x 128ch tile ----------
        __shared__ float tile[64][129];
        _Float16* out = ws + FT_BYTE_OFF / 2;
        const int b = blockIdx.x / (NPIX / 64);
        const int pbase = (blockIdx.x % (NPIX / 64)) * 64;
        const int t = threadIdx.x;
        const float* src = in + (size_t)b * FDIM * NPIX;
        _Float16*    dst = out + (size_t)b * NPIX * FDIM;
        const int tx = t & 63;
        const int cg = t >> 6;
#pragma unroll
        for (int i = 0; i < 32; ++i) {
            int c = cg * 32 + i;
            tile[tx][c] = src[(size_t)c * NPIX + pbase + tx];
        }
        __syncthreads();
        const int sub = t >> 4;
        const int hk  = (t & 15) * 8;
#pragma unroll
        for (int g = 0; g < 4; ++g) {
            const int px = g * 16 + sub;
            f16x8 hv;
#pragma unroll
            for (int j = 0; j < 8; ++j) hv[j] = (_Float16)tile[px][hk + j];
            *(f16x8*)(dst + (size_t)(pbase + px) * FDIM + hk) = hv;
        }
    } else {
        // ---------- pack weights ----------
        const int t = (blockIdx.x - TR_BLOCKS) * 256 + threadIdx.x;  // 0..3071
        const int l = t & 63;
        const int q = l >> 4;
        const int col = l & 15;
        const int frag = t >> 6;  // 0..47
        if (frag < 32) {
            const int kt = frag >> 2, nt = frag & 3;
#pragma unroll
            for (int j = 0; j < 8; ++j) {
                int k = kt * 32 + q * 8 + j;
                int row = (k < 128) ? k : (128 + (k & 1) * 64 + ((k - 128) >> 1));
                ws[((size_t)(frag * 64 + l)) * 8 + j] = (_Float16)W1[row * HDIM + nt * 16 + col];
            }
        } else if (frag < 40) {
            const int f2 = frag - 32;
            const int kt = f2 >> 2, nt = f2 & 3;
#pragma unroll
            for (int j = 0; j < 8; ++j) {
                int row = kt * 32 + q * 8 + j;
                ws[W2_OFF + ((size_t)(f2 * 64 + l)) * 8 + j] = (_Float16)W2[row * HDIM + nt * 16 + col];
            }
        } else {
            const int f3 = frag - 40;
            const int kt = f3 >> 2, nt = f3 & 3;
#pragma unroll
            for (int j = 0; j < 8; ++j) {
                int row = kt * 32 + q * 8 + j;
                ws[W3_OFF + ((size_t)(f3 * 64 + l)) * 8 + j] = (_Float16)W3[row * HDIM + nt * 16 + col];
            }
        }
    }
}

// ---------------- fused decoder: 4 independent waves/block, 64 pts/wave ----------------
__global__ __launch_bounds__(256, 2) void decoder_mfma2(
    const _Float16* __restrict__ ft,   // (B, HW, C) fp16
    const float* __restrict__ points,
    const float* __restrict__ Kmat, const float* __restrict__ Rt,
    const float* __restrict__ Bg,
    const _Float16* __restrict__ wfrag,
    const float* __restrict__ b1, const float* __restrict__ b2,
    const float* __restrict__ b3,
    const float* __restrict__ W4, const float* __restrict__ b4,
    float* __restrict__ out) {
    __shared__ _Float16 lds[4 * 64 * 72];
    const int tid = threadIdx.x;
    const int wid = tid >> 6;
    const int l   = tid & 63;
    const int q   = l >> 4;
    const int col = l & 15;
    // XCD swizzle: batch = blockIdx&7 -> with round-robin block->XCD dispatch,
    // each batch's 802KB feature plane stays in ONE XCD's private L2.
    const int b    = blockIdx.x & 7;
    const int grp  = blockIdx.x >> 3;            // 0..255
    const int base = b * NPTS + grp * 256 + wid * 64;
    const int gid  = base + l;
    _Float16* Ah = lds + wid * 64 * 72;
    float* sh = (float*)Ah;
    int*   shi = (int*)Ah;

    // ---- own point: projection + bilinear weights (verified fp32 chain) ----
    const float px = points[(size_t)gid * 3 + 0];
    const float py = points[(size_t)gid * 3 + 1];
    const float pz = points[(size_t)gid * 3 + 2];
    const float* rt = Rt + b * 12;
    const float* km = Kmat + b * 9;
    float cx = rt[0] * px + rt[1] * py + rt[2]  * pz + rt[3];
    float cy = rt[4] * px + rt[5] * py + rt[6]  * pz + rt[7];
    float cz = rt[8] * px + rt[9] * py + rt[10] * pz + rt[11];
    float ix = km[0] * cx + km[1] * cy + km[2] * cz;
    float iy = km[3] * cx + km[4] * cy + km[5] * cz;
    float iz = km[6] * cx + km[7] * cy + km[8] * cz;
    float z  = iz + 1e-8f;
    float u  = ix / z;
    float v  = iy / z;
    float valid = (iz > 0.0f) ? 1.0f : 0.0f;
    float u_norm = (2.0f * u + 1.0f) / (float)IMG_W - 1.0f;
    float v_norm = (2.0f * v + 1.0f) / (float)IMG_H - 1.0f;
    float x = ((u_norm + 1.0f) * (float)IMG_W - 1.0f) * 0.5f;
    float y = ((v_norm + 1.0f) * (float)IMG_H - 1.0f) * 0.5f;
    float x0f = floorf(x), y0f = floorf(y);
    float wx1 = x - x0f, wy1 = y - y0f;
    float wx0 = 1.0f - wx1, wy0 = 1.0f - wy1;
    int x0 = (int)x0f, y0 = (int)y0f;
    int x1 = x0 + 1, y1 = y0 + 1;
    int x0c = x0 < 0 ? 0 : (x0 > IMG_W - 1 ? IMG_W - 1 : x0);
    int x1c = x1 < 0 ? 0 : (x1 > IMG_W - 1 ? IMG_W - 1 : x1);
    int y0c = y0 < 0 ? 0 : (y0 > IMG_H - 1 ? IMG_H - 1 : y0);
    int y1c = y1 < 0 ? 0 : (y1 > IMG_H - 1 ? IMG_H - 1 : y1);
    float mx0 = (x0 >= 0 && x0 < IMG_W) ? 1.0f : 0.0f;
    float mx1 = (x1 >= 0 && x1 < IMG_W) ? 1.0f : 0.0f;
    float my0 = (y0 >= 0 && y0 < IMG_H) ? 1.0f : 0.0f;
    float my1 = (y1 >= 0 && y1 < IMG_H) ? 1.0f : 0.0f;
    const int pb = b * NPIX;
    sh[l * 12 + 0] = wx0 * wy0 * mx0 * my0 * valid;
    sh[l * 12 + 1] = wx1 * wy0 * mx1 * my0 * valid;
    sh[l * 12 + 2] = wx0 * wy1 * mx0 * my1 * valid;
    sh[l * 12 + 3] = wx1 * wy1 * mx1 * my1 * valid;
    shi[l * 12 + 4] = (pb + y0c * IMG_W + x0c) * FDIM;
    shi[l * 12 + 5] = (pb + y0c * IMG_W + x1c) * FDIM;
    shi[l * 12 + 6] = (pb + y1c * IMG_W + x0c) * FDIM;
    shi[l * 12 + 7] = (pb + y1c * IMG_W + x1c) * FDIM;
    sh[l * 12 + 8]  = px;
    sh[l * 12 + 9]  = py;
    sh[l * 12 + 10] = pz;
    lds_fence();

    const f32x4 zero4 = {0.0f, 0.0f, 0.0f, 0.0f};
    f32x4 acc[4][4];
#pragma unroll
    for (int mt = 0; mt < 4; ++mt)
#pragma unroll
        for (int nt = 0; nt < 4; ++nt) acc[mt][nt] = zero4;

    // read all 4 share records once
    f32x4 wv[4];
    i32x4 iv[4];
    float qx[4], qy[4], qz[4];
#pragma unroll
    for (int mt = 0; mt < 4; ++mt) {
        const float* e = sh + (mt * 16 + col) * 12;
        wv[mt] = *(const f32x4*)(e);
        iv[mt] = *(const i32x4*)(e + 4);
        qx[mt] = e[8]; qy[mt] = e[9]; qz[mt] = e[10];
    }

    // ====== Phase F: Fourier k-tiles 4..7 (pure VALU+MFMA, no memory stalls) ======
    // m = ktf*16 + q*4 + i ; Bg triples loaded once per ktf, reused over all 4 mt
#pragma unroll
    for (int ktf = 0; ktf < 4; ++ktf) {
        float bgx[4], bgy[4], bgz[4];
#pragma unroll
        for (int i = 0; i < 4; ++i) {
            const int m = ktf * 16 + q * 4 + i;
            bgx[i] = Bg[m * 3 + 0];
            bgy[i] = Bg[m * 3 + 1];
            bgz[i] = Bg[m * 3 + 2];
        }
        f16x8 bf[4];
#pragma unroll
        for (int nt = 0; nt < 4; ++nt)
            bf[nt] = *(const f16x8*)(wfrag + ((size_t)(((4 + ktf) * 4 + nt) * 64 + l)) * 8);
#pragma unroll
        for (int mt = 0; mt < 4; ++mt) {
            f16x8 af;
#pragma unroll
            for (int i = 0; i < 4; ++i) {
                float t = bgx[i] * qx[mt] + bgy[i] * qy[mt] + bgz[i] * qz[mt];
                float tf = t - floorf(t);
                af[2 * i]     = (_Float16)__builtin_amdgcn_sinf(tf);
                af[2 * i + 1] = (_Float16)__builtin_amdgcn_cosf(tf);
            }
#pragma unroll
            for (int nt = 0; nt < 4; ++nt)
                acc[mt][nt] = __builtin_amdgcn_mfma_f32_16x16x32_f16(af, bf[nt], acc[mt][nt], 0, 0, 0);
        }
    }

    // ====== Phase I: image k-tiles 0..3, packed-fp16 blend, depth-1 load pipeline ======
#pragma unroll
    for (int mt = 0; mt < 4; ++mt) {
        const _Float16 w0h = (_Float16)wv[mt].x, w1h = (_Float16)wv[mt].y;
        const _Float16 w2h = (_Float16)wv[mt].z, w3h = (_Float16)wv[mt].w;
        const int co0 = q * 8;
        f16x8 c00 = *(const f16x8*)(ft + iv[mt].x + co0);
        f16x8 c10 = *(const f16x8*)(ft + iv[mt].y + co0);
        f16x8 c01 = *(const f16x8*)(ft + iv[mt].z + co0);
        f16x8 c11 = *(const f16x8*)(ft + iv[mt].w + co0);
#pragma unroll
        for (int ktg = 0; ktg < 4; ++ktg) {
            f16x8 n00, n10, n01, n11;
            if (ktg < 3) {
                const int co = (ktg + 1) * 32 + q * 8;
                n00 = *(const f16x8*)(ft + iv[mt].x + co);
                n10 = *(const f16x8*)(ft + iv[mt].y + co);
                n01 = *(const f16x8*)(ft + iv[mt].z + co);
                n11 = *(const f16x8*)(ft + iv[mt].w + co);
            }
            // packed fp16 bilinear blend (v_pk_fma_f16); weights sum<=1, masked->0
            f16x8 af = c00 * w0h + c10 * w1h + c01 * w2h + c11 * w3h;
#pragma unroll
            for (int nt = 0; nt < 4; ++nt) {
                f16x8 bf = *(const f16x8*)(wfrag + ((size_t)((ktg * 4 + nt) * 64 + l)) * 8);
                acc[mt][nt] = __builtin_amdgcn_mfma_f32_16x16x32_f16(af, bf, acc[mt][nt], 0, 0, 0);
            }
            c00 = n00; c10 = n10; c01 = n01; c11 = n11;
        }
    }

    // ---- L1 epilogue: +b1, relu, store h1 in A-layout fp16 (overwrites share) ----
    float bb[4];
#pragma unroll
    for (int nt = 0; nt < 4; ++nt) bb[nt] = b1[nt * 16 + col];
#pragma unroll
    for (int mt = 0; mt < 4; ++mt)
#pragma unroll
        for (int nt = 0; nt < 4; ++nt)
#pragma unroll
            for (int r = 0; r < 4; ++r) {
                float hv = fmaxf(acc[mt][nt][r] + bb[nt], 0.0f);
                Ah[(mt * 16 + q * 4 + r) * 72 + nt * 16 + col] = (_Float16)hv;
            }
    lds_fence();

    // ================= layer 2 =================
#pragma unroll
    for (int mt = 0; mt < 4; ++mt)
#pragma unroll
        for (int nt = 0; nt < 4; ++nt) acc[mt][nt] = zero4;
#pragma unroll
    for (int ktl = 0; ktl < 2; ++ktl) {
        f16x8 bf[4];
#pragma unroll
        for (int nt = 0; nt < 4; ++nt)
            bf[nt] = *(const f16x8*)(wfrag + W2_OFF + ((size_t)((ktl * 4 + nt) * 64 + l)) * 8);
#pragma unroll
        for (int mt = 0; mt < 4; ++mt) {
            f16x8 af = *(const f16x8*)(&Ah[(mt * 16 + col) * 72 + ktl * 32 + q * 8]);
#pragma unroll
            for (int nt = 0; nt < 4; ++nt)
                acc[mt][nt] = __builtin_amdgcn_mfma_f32_16x16x32_f16(af, bf[nt], acc[mt][nt], 0, 0, 0);
        }
    }
    lds_fence();
#pragma unroll
    for (int nt = 0; nt < 4; ++nt) bb[nt] = b2[nt * 16 + col];
#pragma unroll
    for (int mt = 0; mt < 4; ++mt)
#pragma unroll
        for (int nt = 0; nt < 4; ++nt)
#pragma unroll
            for (int r = 0; r < 4; ++r) {
                float hv = fmaxf(acc[mt][nt][r] + bb[nt], 0.0f);
                Ah[(mt * 16 + q * 4 + r) * 72 + nt * 16 + col] = (_Float16)hv;
            }
    lds_fence();

    // ================= layer 3 =================
#pragma unroll
    for (int mt = 0; mt < 4; ++mt)
#pragma unroll
        for (int nt = 0; nt < 4; ++nt) acc[mt][nt] = zero4;
#pragma unroll
    for (int ktl = 0; ktl < 2; ++ktl) {
        f16x8 bf[4];
#pragma unroll
        for (int nt = 0; nt < 4; ++nt)
            bf[nt] = *(const f16x8*)(wfrag + W3_OFF + ((size_t)((ktl * 4 + nt) * 64 + l)) * 8);
#pragma unroll
        for (int mt = 0; mt < 4; ++mt) {
            f16x8 af = *(const f16x8*)(&Ah[(mt * 16 + col) * 72 + ktl * 32 + q * 8]);
#pragma unroll
            for (int nt = 0; nt < 4; ++nt)
                acc[mt][nt] = __builtin_amdgcn_mfma_f32_16x16x32_f16(af, bf[nt], acc[mt][nt], 0, 0, 0);
        }
    }

    // ================= layer 4: relu + dot(W4) + 16-lane shfl reduction =================
    float b3v[4], w4v[4];
#pragma unroll
    for (int nt = 0; nt < 4; ++nt) {
        b3v[nt] = b3[nt * 16 + col];
        w4v[nt] = W4[nt * 16 + col];
    }
    const float b4v = b4[0];
#pragma unroll
    for (int mt = 0; mt < 4; ++mt)
#pragma unroll
        for (int r = 0; r < 4; ++r) {
            float p = 0.0f;
#pragma unroll
            for (int nt = 0; nt < 4; ++nt)
                p = fmaf(fmaxf(acc[mt][nt][r] + b3v[nt], 0.0f), w4v[nt], p);
            p += __shfl_xor(p, 1);
            p += __shfl_xor(p, 2);
            p += __shfl_xor(p, 4);
            p += __shfl_xor(p, 8);
            if (col == 0) out[base + mt * 16 + q * 4 + r] = p + b4v;
        }
}

// ---------------- fallback: verified R1 pure-VALU kernel ----------------
__global__ __launch_bounds__(64, 2) void decoder_valu(
    const float* __restrict__ feats, const float* __restrict__ points,
    const float* __restrict__ Kmat, const float* __restrict__ Rt,
    const float* __restrict__ Bg,
    const float* __restrict__ W1, const float* __restrict__ b1,
    const float* __restrict__ W2, const float* __restrict__ b2,
    const float* __restrict__ W3, const float* __restrict__ b3,
    const float* __restrict__ W4, const float* __restrict__ b4,
    float* __restrict__ out) {
    __shared__ float hbuf[64 * 65];
    const int tid = threadIdx.x;
    const int b   = blockIdx.x / (NPTS / 64);
    const int gid = blockIdx.x * 64 + tid;
    const float px = points[(size_t)gid * 3 + 0];
    const float py = points[(size_t)gid * 3 + 1];
    const float pz = points[(size_t)gid * 3 + 2];
    const float* rt = Rt + b * 12;
    const float* km = Kmat + b * 9;
    float cx = rt[0] * px + rt[1] * py + rt[2]  * pz + rt[3];
    float cy = rt[4] * px + rt[5] * py + rt[6]  * pz + rt[7];
    float cz = rt[8] * px + rt[9] * py + rt[10] * pz + rt[11];
    float ix = km[0] * cx + km[1] * cy + km[2] * cz;
    float iy = km[3] * cx + km[4] * cy + km[5] * cz;
    float iz = km[6] * cx + km[7] * cy + km[8] * cz;
    float z  = iz + 1e-8f;
    float u  = ix / z, v = iy / z;
    float valid = (iz > 0.0f) ? 1.0f : 0.0f;
    float u_norm = (2.0f * u + 1.0f) / (float)IMG_W - 1.0f;
    float v_norm = (2.0f * v + 1.0f) / (float)IMG_H - 1.0f;
    float x = ((u_norm + 1.0f) * (float)IMG_W - 1.0f) * 0.5f;
    float y = ((v_norm + 1.0f) * (float)IMG_H - 1.0f) * 0.5f;
    float x0f = floorf(x), y0f = floorf(y);
    float wx1 = x - x0f, wy1 = y - y0f;
    float wx0 = 1.0f - wx1, wy0 = 1.0f - wy1;
    int x0 = (int)x0f, y0 = (int)y0f;
    int x1 = x0 + 1, y1 = y0 + 1;
    int x0c = x0 < 0 ? 0 : (x0 > IMG_W - 1 ? IMG_W - 1 : x0);
    int x1c = x1 < 0 ? 0 : (x1 > IMG_W - 1 ? IMG_W - 1 : x1);
    int y0c = y0 < 0 ? 0 : (y0 > IMG_H - 1 ? IMG_H - 1 : y0);
    int y1c = y1 < 0 ? 0 : (y1 > IMG_H - 1 ? IMG_H - 1 : y1);
    float mx0 = (x0 >= 0 && x0 < IMG_W) ? 1.0f : 0.0f;
    float mx1 = (x1 >= 0 && x1 < IMG_W) ? 1.0f : 0.0f;
    float my0 = (y0 >= 0 && y0 < IMG_H) ? 1.0f : 0.0f;
    float my1 = (y1 >= 0 && y1 < IMG_H) ? 1.0f : 0.0f;
    float w00 = wx0 * wy0 * mx0 * my0 * valid;
    float w10 = wx1 * wy0 * mx1 * my0 * valid;
    float w01 = wx0 * wy1 * mx0 * my1 * valid;
    float w11 = wx1 * wy1 * mx1 * my1 * valid;
    float h[HDIM];
#pragma unroll
    for (int j = 0; j < HDIM; ++j) h[j] = b1[j];
    const float* fb = feats + (size_t)b * FDIM * NPIX;
    const int p00 = y0c * IMG_W + x0c, p10 = y0c * IMG_W + x1c;
    const int p01 = y1c * IMG_W + x0c, p11 = y1c * IMG_W + x1c;
#pragma unroll 1
    for (int c = 0; c < FDIM; ++c) {
        const float* fp = fb + (size_t)c * NPIX;
        float fv = w00 * fp[p00] + w10 * fp[p10] + w01 * fp[p01] + w11 * fp[p11];
        const float* wr = W1 + (size_t)c * HDIM;
#pragma unroll
        for (int j = 0; j < HDIM; ++j) h[j] = fmaf(fv, wr[j], h[j]);
    }
#pragma unroll 1
    for (int m = 0; m < MSIZE; ++m) {
        float t = Bg[m * 3 + 0] * px + Bg[m * 3 + 1] * py + Bg[m * 3 + 2] * pz;
        float tf = t - floorf(t);
        float s = __builtin_amdgcn_sinf(tf);
        float c = __builtin_amdgcn_cosf(tf);
        const float* wsn = W1 + (size_t)(FDIM + m) * HDIM;
        const float* wcs = W1 + (size_t)(FDIM + MSIZE + m) * HDIM;
#pragma unroll
        for (int j = 0; j < HDIM; ++j)
            h[j] = fmaf(s, wsn[j], fmaf(c, wcs[j], h[j]));
    }
    float* myh = &hbuf[tid * 65];
#pragma unroll
    for (int j = 0; j < HDIM; ++j) myh[j] = fmaxf(h[j], 0.0f);
    float h2[HDIM];
#pragma unroll
    for (int j = 0; j < HDIM; ++j) h2[j] = b2[j];
#pragma unroll 1
    for (int i = 0; i < HDIM; ++i) {
        float hi = myh[i];
        const float* wr = W2 + (size_t)i * HDIM;
#pragma unroll
        for (int j = 0; j < HDIM; ++j) h2[j] = fmaf(hi, wr[j], h2[j]);
    }
#pragma unroll
    for (int j = 0; j < HDIM; ++j) myh[j] = fmaxf(h2[j], 0.0f);
#pragma unroll
    for (int j = 0; j < HDIM; ++j) h[j] = b3[j];
#pragma unroll 1
    for (int i = 0; i < HDIM; ++i) {
        float hi = myh[i];
        const float* wr = W3 + (size_t)i * HDIM;
#pragma unroll
        for (int j = 0; j < HDIM; ++j) h[j] = fmaf(hi, wr[j], h[j]);
    }
    float acc = b4[0];
#pragma unroll
    for (int j = 0; j < HDIM; ++j) acc = fmaf(fmaxf(h[j], 0.0f), W4[j], acc);
    out[gid] = acc;
}

extern "C" void kernel_launch(void* const* d_in, const int* in_sizes, int n_in,
                              void* d_out, int out_size, void* d_ws, size_t ws_size,
                              hipStream_t stream) {
    const float* feats = (const float*)d_in[0];
    const float* pts   = (const float*)d_in[1];
    const float* k     = (const float*)d_in[2];
    const float* rt    = (const float*)d_in[3];
    const float* Bg    = (const float*)d_in[4];
    const float* W1    = (const float*)d_in[5];
    const float* b1    = (const float*)d_in[6];
    const float* W2    = (const float*)d_in[7];
    const float* b2    = (const float*)d_in[8];
    const float* W3    = (const float*)d_in[9];
    const float* b3    = (const float*)d_in[10];
    const float* W4    = (const float*)d_in[11];
    const float* b4    = (const float*)d_in[12];
    float* out = (float*)d_out;

    const size_t ftBytes = (size_t)NB * NPIX * FDIM * sizeof(_Float16);

    if (ws_size >= FT_BYTE_OFF + ftBytes) {
        _Float16* wf = (_Float16*)d_ws;
        _Float16* ft = (_Float16*)((char*)d_ws + FT_BYTE_OFF);
        prep_kernel<<<TR_BLOCKS + 12, 256, 0, stream>>>(feats, W1, W2, W3, wf);
        decoder_mfma2<<<NB * NPTS / 256, 256, 0, stream>>>(ft, pts, k, rt, Bg, wf,
                                                           b1, b2, b3, W4, b4, out);
    } else {
        decoder_valu<<<NB * NPTS / 64, 64, 0, stream>>>(feats, pts, k, rt, Bg,
                                                        W1, b1, W2, b2, W3, b3, W4, b4, out);
    }
}

// Round 7
// 182.322 us; speedup vs baseline: 2.3121x; 1.0099x over previous
//
#include <hip/hip_runtime.h>

#define FDIM 128
#define HDIM 64
#define MSIZE 64
#define IMG_W 56
#define IMG_H 56
#define NPIX (IMG_W * IMG_H)
#define NB 8
#define NPTS 65536

typedef _Float16 f16x8 __attribute__((ext_vector_type(8)));
typedef __fp16 hf16x2 __attribute__((ext_vector_type(2)));   // return type of cvt_pkrtz
typedef float f32x4 __attribute__((ext_vector_type(4)));
typedef int i32x4 __attribute__((ext_vector_type(4)));

// d_ws layout:
//   [0, 32768)     : W1 fragments fp16 (8kt*4nt*64lane*8)
//   [32768, 40960) : W2 fragments
//   [40960, 49152) : W3 fragments
//   [49152, +6.4MB): transposed features (B, H*W, C) fp16
#define W2_OFF 16384   // in halves
#define W3_OFF 20480
#define FT_BYTE_OFF 49152
#define TR16_BLOCKS (NPIX / 16 * NB)   // 1568

// wave-local LDS fence: orders this wave's ds ops without the full
// vmcnt(0)+barrier drain __syncthreads forces.
__device__ __forceinline__ void lds_fence() {
    __asm__ volatile("s_waitcnt lgkmcnt(0)" ::: "memory");
}

// ---- fused prep ----
// blocks [0,1568): transpose feats fp32 (B,C,H,W) -> fp16 (B,HW,C), 16px x 128ch tiles,
//                  float4 coalesced reads, f16x8 coalesced writes.
// blocks [1568,1580): pack W1/W2/W3 into MFMA B-fragment order.
// frag elem j of lane l, tile (kt,nt): B[k = kt*32 + (l>>4)*8 + j][n = nt*16 + (l&15)]
// W1 k-perm: k<128 -> img channel k; k>=128 -> row = 128 + (k&1)*64 + ((k-128)>>1)
// (decoder emits interleaved (sin_m, cos_m); must match exactly.)
__global__ __launch_bounds__(256) void prep_kernel(const float* __restrict__ in,
                                                   const float* __restrict__ W1,
                                                   const float* __restrict__ W2,
                                                   const float* __restrict__ W3,
                                                   _Float16* __restrict__ ws) {
    if (blockIdx.x < TR16_BLOCKS) {
        __shared__ float tile[16][133];
        _Float16* out = ws + FT_BYTE_OFF / 2;
        const int b = blockIdx.x / (NPIX / 16);
        const int pbase = (blockIdx.x % (NPIX / 16)) * 16;
        const int t = threadIdx.x;
        const float* src = in + (size_t)b * FDIM * NPIX;
        _Float16*    dst = out + (size_t)b * NPIX * FDIM;
        const int pq = t & 3;    // pixel quad 0..3
        const int ch = t >> 2;   // 0..63
#pragma unroll
        for (int it = 0; it < 2; ++it) {
            const int c = it * 64 + ch;
            const float4 v = *(const float4*)(src + (size_t)c * NPIX + pbase + pq * 4);
            tile[pq * 4 + 0][c] = v.x;
            tile[pq * 4 + 1][c] = v.y;
            tile[pq * 4 + 2][c] = v.z;
            tile[pq * 4 + 3][c] = v.w;
        }
        __syncthreads();
        const int px = t >> 4;
        const int hk = (t & 15) * 8;
        union { f16x8 v; hf16x2 h[4]; } hv;
#pragma unroll
        for (int j = 0; j < 4; ++j)
            hv.h[j] = __builtin_amdgcn_cvt_pkrtz(tile[px][hk + 2 * j], tile[px][hk + 2 * j + 1]);
        *(f16x8*)(dst + (size_t)(pbase + px) * FDIM + hk) = hv.v;
    } else {
        const int t = (blockIdx.x - TR16_BLOCKS) * 256 + threadIdx.x;  // 0..3071
        const int l = t & 63;
        const int q = l >> 4;
        const int col = l & 15;
        const int frag = t >> 6;  // 0..47
        if (frag < 32) {
            const int kt = frag >> 2, nt = frag & 3;
#pragma unroll
            for (int j = 0; j < 8; ++j) {
                int k = kt * 32 + q * 8 + j;
                int row = (k < 128) ? k : (128 + (k & 1) * 64 + ((k - 128) >> 1));
                ws[((size_t)(frag * 64 + l)) * 8 + j] = (_Float16)W1[row * HDIM + nt * 16 + col];
            }
        } else if (frag < 40) {
            const int f2 = frag - 32;
            const int kt = f2 >> 2, nt = f2 & 3;
#pragma unroll
            for (int j = 0; j < 8; ++j) {
                int row = kt * 32 + q * 8 + j;
                ws[W2_OFF + ((size_t)(f2 * 64 + l)) * 8 + j] = (_Float16)W2[row * HDIM + nt * 16 + col];
            }
        } else {
            const int f3 = frag - 40;
            const int kt = f3 >> 2, nt = f3 & 3;
#pragma unroll
            for (int j = 0; j < 8; ++j) {
                int row = kt * 32 + q * 8 + j;
                ws[W3_OFF + ((size_t)(f3 * 64 + l)) * 8 + j] = (_Float16)W3[row * HDIM + nt * 16 + col];
            }
        }
    }
}

// ---------------- fused decoder: 4 independent waves/block, 32 pts/wave ----------------
// M=32: acc = 2x4 f32x4 = 32 AGPRs; (256,4) caps unified VGPR+AGPR at 128 -> 4 waves/SIMD.
__global__ __launch_bounds__(256, 4) void decoder_mfma3(
    const _Float16* __restrict__ ft,   // (B, HW, C) fp16
    const float* __restrict__ points,
    const float* __restrict__ Kmat, const float* __restrict__ Rt,
    const float* __restrict__ Bg,
    const _Float16* __restrict__ wfrag,
    const float* __restrict__ b1, const float* __restrict__ b2,
    const float* __restrict__ b3,
    const float* __restrict__ W4, const float* __restrict__ b4,
    float* __restrict__ out) {
    __shared__ _Float16 lds[4 * 32 * 72];   // 18432 B
    const int tid = threadIdx.x;
    const int wid = tid >> 6;
    const int l   = tid & 63;
    const int q   = l >> 4;
    const int col = l & 15;
    // XCD swizzle: batch = blockIdx&7 -> each batch's 802KB fp16 plane stays in one XCD L2.
    const int b    = blockIdx.x & 7;
    const int grp  = blockIdx.x >> 3;            // 0..511
    const int base = b * NPTS + grp * 128 + wid * 32;
    _Float16* Ah = lds + wid * 32 * 72;
    float* sh = (float*)Ah;
    int*   shi = (int*)Ah;

    // ---- lanes 0..31: own point projection + bilinear record (verified fp32 chain) ----
    if (l < 32) {
        const int gid = base + l;
        const float px = points[(size_t)gid * 3 + 0];
        const float py = points[(size_t)gid * 3 + 1];
        const float pz = points[(size_t)gid * 3 + 2];
        const float* rt = Rt + b * 12;
        const float* km = Kmat + b * 9;
        float cx = rt[0] * px + rt[1] * py + rt[2]  * pz + rt[3];
        float cy = rt[4] * px + rt[5] * py + rt[6]  * pz + rt[7];
        float cz = rt[8] * px + rt[9] * py + rt[10] * pz + rt[11];
        float ix = km[0] * cx + km[1] * cy + km[2] * cz;
        float iy = km[3] * cx + km[4] * cy + km[5] * cz;
        float iz = km[6] * cx + km[7] * cy + km[8] * cz;
        float z  = iz + 1e-8f;
        float u  = ix / z;
        float v  = iy / z;
        float valid = (iz > 0.0f) ? 1.0f : 0.0f;
        float u_norm = (2.0f * u + 1.0f) / (float)IMG_W - 1.0f;
        float v_norm = (2.0f * v + 1.0f) / (float)IMG_H - 1.0f;
        float x = ((u_norm + 1.0f) * (float)IMG_W - 1.0f) * 0.5f;
        float y = ((v_norm + 1.0f) * (float)IMG_H - 1.0f) * 0.5f;
        float x0f = floorf(x), y0f = floorf(y);
        float wx1 = x - x0f, wy1 = y - y0f;
        float wx0 = 1.0f - wx1, wy0 = 1.0f - wy1;
        int x0 = (int)x0f, y0 = (int)y0f;
        int x1 = x0 + 1, y1 = y0 + 1;
        int x0c = x0 < 0 ? 0 : (x0 > IMG_W - 1 ? IMG_W - 1 : x0);
        int x1c = x1 < 0 ? 0 : (x1 > IMG_W - 1 ? IMG_W - 1 : x1);
        int y0c = y0 < 0 ? 0 : (y0 > IMG_H - 1 ? IMG_H - 1 : y0);
        int y1c = y1 < 0 ? 0 : (y1 > IMG_H - 1 ? IMG_H - 1 : y1);
        float mx0 = (x0 >= 0 && x0 < IMG_W) ? 1.0f : 0.0f;
        float mx1 = (x1 >= 0 && x1 < IMG_W) ? 1.0f : 0.0f;
        float my0 = (y0 >= 0 && y0 < IMG_H) ? 1.0f : 0.0f;
        float my1 = (y1 >= 0 && y1 < IMG_H) ? 1.0f : 0.0f;
        const int pb = b * NPIX;
        sh[l * 12 + 0] = wx0 * wy0 * mx0 * my0 * valid;
        sh[l * 12 + 1] = wx1 * wy0 * mx1 * my0 * valid;
        sh[l * 12 + 2] = wx0 * wy1 * mx0 * my1 * valid;
        sh[l * 12 + 3] = wx1 * wy1 * mx1 * my1 * valid;
        shi[l * 12 + 4] = (pb + y0c * IMG_W + x0c) * FDIM;
        shi[l * 12 + 5] = (pb + y0c * IMG_W + x1c) * FDIM;
        shi[l * 12 + 6] = (pb + y1c * IMG_W + x0c) * FDIM;
        shi[l * 12 + 7] = (pb + y1c * IMG_W + x1c) * FDIM;
        sh[l * 12 + 8]  = px;
        sh[l * 12 + 9]  = py;
        sh[l * 12 + 10] = pz;
    }
    lds_fence();

    const f32x4 zero4 = {0.0f, 0.0f, 0.0f, 0.0f};
    f32x4 acc[2][4];
#pragma unroll
    for (int mt = 0; mt < 2; ++mt)
#pragma unroll
        for (int nt = 0; nt < 4; ++nt) acc[mt][nt] = zero4;

    // capture records (A-tile epilogue will overwrite them)
    f32x4 wv[2];
    i32x4 iv[2];
    float qx[2], qy[2], qz[2];
#pragma unroll
    for (int mt = 0; mt < 2; ++mt) {
        const float* e = sh + (mt * 16 + col) * 12;
        wv[mt] = *(const f32x4*)(e);
        iv[mt] = *(const i32x4*)(e + 4);
        qx[mt] = e[8]; qy[mt] = e[9]; qz[mt] = e[10];
    }

    // pre-issue first corner-load group (mt=0, ktg=0) so phase F hides its latency
    f16x8 c00 = *(const f16x8*)(ft + iv[0].x + q * 8);
    f16x8 c10 = *(const f16x8*)(ft + iv[0].y + q * 8);
    f16x8 c01 = *(const f16x8*)(ft + iv[0].z + q * 8);
    f16x8 c11 = *(const f16x8*)(ft + iv[0].w + q * 8);

    // ====== Phase F: Fourier k-tiles 4..7 (pure VALU/trans + MFMA) ======
    // m = ktf*16 + q*4 + i; af pairs (sin,cos) packed via v_cvt_pkrtz
#pragma unroll
    for (int ktf = 0; ktf < 4; ++ktf) {
        float bgx[4], bgy[4], bgz[4];
#pragma unroll
        for (int i = 0; i < 4; ++i) {
            const int m = ktf * 16 + q * 4 + i;
            bgx[i] = Bg[m * 3 + 0];
            bgy[i] = Bg[m * 3 + 1];
            bgz[i] = Bg[m * 3 + 2];
        }
        f16x8 bf[4];
#pragma unroll
        for (int nt = 0; nt < 4; ++nt)
            bf[nt] = *(const f16x8*)(wfrag + ((size_t)(((4 + ktf) * 4 + nt) * 64 + l)) * 8);
#pragma unroll
        for (int mt = 0; mt < 2; ++mt) {
            union { f16x8 v; hf16x2 h[4]; } af;
#pragma unroll
            for (int i = 0; i < 4; ++i) {
                float t = bgx[i] * qx[mt] + bgy[i] * qy[mt] + bgz[i] * qz[mt];
                float tf = __builtin_amdgcn_fractf(t);
                af.h[i] = __builtin_amdgcn_cvt_pkrtz(__builtin_amdgcn_sinf(tf),
                                                     __builtin_amdgcn_cosf(tf));
            }
#pragma unroll
            for (int nt = 0; nt < 4; ++nt)
                acc[mt][nt] = __builtin_amdgcn_mfma_f32_16x16x32_f16(af.v, bf[nt], acc[mt][nt], 0, 0, 0);
        }
    }

    // ====== Phase I: image k-tiles 0..3 x mt 0..1, flat loop, depth-1 prefetch ======
    _Float16 wh[2][4];
#pragma unroll
    for (int mt = 0; mt < 2; ++mt) {
        wh[mt][0] = (_Float16)wv[mt].x; wh[mt][1] = (_Float16)wv[mt].y;
        wh[mt][2] = (_Float16)wv[mt].z; wh[mt][3] = (_Float16)wv[mt].w;
    }
#pragma unroll
    for (int s = 0; s < 8; ++s) {
        const int mt = s >> 2, ktg = s & 3;
        f16x8 n00, n10, n01, n11;
        if (s < 7) {
            const int nmt = (s + 1) >> 2, nktg = (s + 1) & 3;
            const int co = nktg * 32 + q * 8;
            n00 = *(const f16x8*)(ft + iv[nmt].x + co);
            n10 = *(const f16x8*)(ft + iv[nmt].y + co);
            n01 = *(const f16x8*)(ft + iv[nmt].z + co);
            n11 = *(const f16x8*)(ft + iv[nmt].w + co);
        }
        // packed fp16 bilinear blend (v_pk_mul/v_pk_fma)
        f16x8 af = c00 * wh[mt][0] + c10 * wh[mt][1] + c01 * wh[mt][2] + c11 * wh[mt][3];
#pragma unroll
        for (int nt = 0; nt < 4; ++nt) {
            f16x8 bf = *(const f16x8*)(wfrag + ((size_t)((ktg * 4 + nt) * 64 + l)) * 8);
            acc[mt][nt] = __builtin_amdgcn_mfma_f32_16x16x32_f16(af, bf, acc[mt][nt], 0, 0, 0);
        }
        c00 = n00; c10 = n10; c01 = n01; c11 = n11;
    }

    // ---- L1 epilogue: +b1, relu, store h1 in A-layout fp16 (overwrites records) ----
    float bb[4];
#pragma unroll
    for (int nt = 0; nt < 4; ++nt) bb[nt] = b1[nt * 16 + col];
#pragma unroll
    for (int mt = 0; mt < 2; ++mt)
#pragma unroll
        for (int nt = 0; nt < 4; ++nt)
#pragma unroll
            for (int r = 0; r < 4; ++r) {
                float hv = fmaxf(acc[mt][nt][r] + bb[nt], 0.0f);
                Ah[(mt * 16 + q * 4 + r) * 72 + nt * 16 + col] = (_Float16)hv;
            }
    lds_fence();

    // ================= layer 2 =================
#pragma unroll
    for (int mt = 0; mt < 2; ++mt)
#pragma unroll
        for (int nt = 0; nt < 4; ++nt) acc[mt][nt] = zero4;
#pragma unroll
    for (int ktl = 0; ktl < 2; ++ktl) {
        f16x8 bf[4];
#pragma unroll
        for (int nt = 0; nt < 4; ++nt)
            bf[nt] = *(const f16x8*)(wfrag + W2_OFF + ((size_t)((ktl * 4 + nt) * 64 + l)) * 8);
#pragma unroll
        for (int mt = 0; mt < 2; ++mt) {
            f16x8 af = *(const f16x8*)(&Ah[(mt * 16 + col) * 72 + ktl * 32 + q * 8]);
#pragma unroll
            for (int nt = 0; nt < 4; ++nt)
                acc[mt][nt] = __builtin_amdgcn_mfma_f32_16x16x32_f16(af, bf[nt], acc[mt][nt], 0, 0, 0);
        }
    }
    lds_fence();
#pragma unroll
    for (int nt = 0; nt < 4; ++nt) bb[nt] = b2[nt * 16 + col];
#pragma unroll
    for (int mt = 0; mt < 2; ++mt)
#pragma unroll
        for (int nt = 0; nt < 4; ++nt)
#pragma unroll
            for (int r = 0; r < 4; ++r) {
                float hv = fmaxf(acc[mt][nt][r] + bb[nt], 0.0f);
                Ah[(mt * 16 + q * 4 + r) * 72 + nt * 16 + col] = (_Float16)hv;
            }
    lds_fence();

    // ================= layer 3 =================
#pragma unroll
    for (int mt = 0; mt < 2; ++mt)
#pragma unroll
        for (int nt = 0; nt < 4; ++nt) acc[mt][nt] = zero4;
#pragma unroll
    for (int ktl = 0; ktl < 2; ++ktl) {
        f16x8 bf[4];
#pragma unroll
        for (int nt = 0; nt < 4; ++nt)
            bf[nt] = *(const f16x8*)(wfrag + W3_OFF + ((size_t)((ktl * 4 + nt) * 64 + l)) * 8);
#pragma unroll
        for (int mt = 0; mt < 2; ++mt) {
            f16x8 af = *(const f16x8*)(&Ah[(mt * 16 + col) * 72 + ktl * 32 + q * 8]);
#pragma unroll
            for (int nt = 0; nt < 4; ++nt)
                acc[mt][nt] = __builtin_amdgcn_mfma_f32_16x16x32_f16(af, bf[nt], acc[mt][nt], 0, 0, 0);
        }
    }

    // ================= layer 4: relu + dot(W4) + 16-lane shfl reduction =================
    float b3v[4], w4v[4];
#pragma unroll
    for (int nt = 0; nt < 4; ++nt) {
        b3v[nt] = b3[nt * 16 + col];
        w4v[nt] = W4[nt * 16 + col];
    }
    const float b4v = b4[0];
#pragma unroll
    for (int mt = 0; mt < 2; ++mt)
#pragma unroll
        for (int r = 0; r < 4; ++r) {
            float p = 0.0f;
#pragma unroll
            for (int nt = 0; nt < 4; ++nt)
                p = fmaf(fmaxf(acc[mt][nt][r] + b3v[nt], 0.0f), w4v[nt], p);
            p += __shfl_xor(p, 1);
            p += __shfl_xor(p, 2);
            p += __shfl_xor(p, 4);
            p += __shfl_xor(p, 8);
            if (col == 0) out[base + mt * 16 + q * 4 + r] = p + b4v;
        }
}

// ---------------- fallback: verified R1 pure-VALU kernel ----------------
__global__ __launch_bounds__(64, 2) void decoder_valu(
    const float* __restrict__ feats, const float* __restrict__ points,
    const float* __restrict__ Kmat, const float* __restrict__ Rt,
    const float* __restrict__ Bg,
    const float* __restrict__ W1, const float* __restrict__ b1,
    const float* __restrict__ W2, const float* __restrict__ b2,
    const float* __restrict__ W3, const float* __restrict__ b3,
    const float* __restrict__ W4, const float* __restrict__ b4,
    float* __restrict__ out) {
    __shared__ float hbuf[64 * 65];
    const int tid = threadIdx.x;
    const int b   = blockIdx.x / (NPTS / 64);
    const int gid = blockIdx.x * 64 + tid;
    const float px = points[(size_t)gid * 3 + 0];
    const float py = points[(size_t)gid * 3 + 1];
    const float pz = points[(size_t)gid * 3 + 2];
    const float* rt = Rt + b * 12;
    const float* km = Kmat + b * 9;
    float cx = rt[0] * px + rt[1] * py + rt[2]  * pz + rt[3];
    float cy = rt[4] * px + rt[5] * py + rt[6]  * pz + rt[7];
    float cz = rt[8] * px + rt[9] * py + rt[10] * pz + rt[11];
    float ix = km[0] * cx + km[1] * cy + km[2] * cz;
    float iy = km[3] * cx + km[4] * cy + km[5] * cz;
    float iz = km[6] * cx + km[7] * cy + km[8] * cz;
    float z  = iz + 1e-8f;
    float u  = ix / z, v = iy / z;
    float valid = (iz > 0.0f) ? 1.0f : 0.0f;
    float u_norm = (2.0f * u + 1.0f) / (float)IMG_W - 1.0f;
    float v_norm = (2.0f * v + 1.0f) / (float)IMG_H - 1.0f;
    float x = ((u_norm + 1.0f) * (float)IMG_W - 1.0f) * 0.5f;
    float y = ((v_norm + 1.0f) * (float)IMG_H - 1.0f) * 0.5f;
    float x0f = floorf(x), y0f = floorf(y);
    float wx1 = x - x0f, wy1 = y - y0f;
    float wx0 = 1.0f - wx1, wy0 = 1.0f - wy1;
    int x0 = (int)x0f, y0 = (int)y0f;
    int x1 = x0 + 1, y1 = y0 + 1;
    int x0c = x0 < 0 ? 0 : (x0 > IMG_W - 1 ? IMG_W - 1 : x0);
    int x1c = x1 < 0 ? 0 : (x1 > IMG_W - 1 ? IMG_W - 1 : x1);
    int y0c = y0 < 0 ? 0 : (y0 > IMG_H - 1 ? IMG_H - 1 : y0);
    int y1c = y1 < 0 ? 0 : (y1 > IMG_H - 1 ? IMG_H - 1 : y1);
    float mx0 = (x0 >= 0 && x0 < IMG_W) ? 1.0f : 0.0f;
    float mx1 = (x1 >= 0 && x1 < IMG_W) ? 1.0f : 0.0f;
    float my0 = (y0 >= 0 && y0 < IMG_H) ? 1.0f : 0.0f;
    float my1 = (y1 >= 0 && y1 < IMG_H) ? 1.0f : 0.0f;
    float w00 = wx0 * wy0 * mx0 * my0 * valid;
    float w10 = wx1 * wy0 * mx1 * my0 * valid;
    float w01 = wx0 * wy1 * mx0 * my1 * valid;
    float w11 = wx1 * wy1 * mx1 * my1 * valid;
    float h[HDIM];
#pragma unroll
    for (int j = 0; j < HDIM; ++j) h[j] = b1[j];
    const float* fb = feats + (size_t)b * FDIM * NPIX;
    const int p00 = y0c * IMG_W + x0c, p10 = y0c * IMG_W + x1c;
    const int p01 = y1c * IMG_W + x0c, p11 = y1c * IMG_W + x1c;
#pragma unroll 1
    for (int c = 0; c < FDIM; ++c) {
        const float* fp = fb + (size_t)c * NPIX;
        float fv = w00 * fp[p00] + w10 * fp[p10] + w01 * fp[p01] + w11 * fp[p11];
        const float* wr = W1 + (size_t)c * HDIM;
#pragma unroll
        for (int j = 0; j < HDIM; ++j) h[j] = fmaf(fv, wr[j], h[j]);
    }
#pragma unroll 1
    for (int m = 0; m < MSIZE; ++m) {
        float t = Bg[m * 3 + 0] * px + Bg[m * 3 + 1] * py + Bg[m * 3 + 2] * pz;
        float tf = t - floorf(t);
        float s = __builtin_amdgcn_sinf(tf);
        float c = __builtin_amdgcn_cosf(tf);
        const float* wsn = W1 + (size_t)(FDIM + m) * HDIM;
        const float* wcs = W1 + (size_t)(FDIM + MSIZE + m) * HDIM;
#pragma unroll
        for (int j = 0; j < HDIM; ++j)
            h[j] = fmaf(s, wsn[j], fmaf(c, wcs[j], h[j]));
    }
    float* myh = &hbuf[tid * 65];
#pragma unroll
    for (int j = 0; j < HDIM; ++j) myh[j] = fmaxf(h[j], 0.0f);
    float h2[HDIM];
#pragma unroll
    for (int j = 0; j < HDIM; ++j) h2[j] = b2[j];
#pragma unroll 1
    for (int i = 0; i < HDIM; ++i) {
        float hi = myh[i];
        const float* wr = W2 + (size_t)i * HDIM;
#pragma unroll
        for (int j = 0; j < HDIM; ++j) h2[j] = fmaf(hi, wr[j], h2[j]);
    }
#pragma unroll
    for (int j = 0; j < HDIM; ++j) myh[j] = fmaxf(h2[j], 0.0f);
#pragma unroll
    for (int j = 0; j < HDIM; ++j) h[j] = b3[j];
#pragma unroll 1
    for (int i = 0; i < HDIM; ++i) {
        float hi = myh[i];
        const float* wr = W3 + (size_t)i * HDIM;
#pragma unroll
        for (int j = 0; j < HDIM; ++j) h[j] = fmaf(hi, wr[j], h[j]);
    }
    float acc = b4[0];
#pragma unroll
    for (int j = 0; j < HDIM; ++j) acc = fmaf(fmaxf(h[j], 0.0f), W4[j], acc);
    out[gid] = acc;
}

extern "C" void kernel_launch(void* const* d_in, const int* in_sizes, int n_in,
                              void* d_out, int out_size, void* d_ws, size_t ws_size,
                              hipStream_t stream) {
    const float* feats = (const float*)d_in[0];
    const float* pts   = (const float*)d_in[1];
    const float* k     = (const float*)d_in[2];
    const float* rt    = (const float*)d_in[3];
    const float* Bg    = (const float*)d_in[4];
    const float* W1    = (const float*)d_in[5];
    const float* b1    = (const float*)d_in[6];
    const float* W2    = (const float*)d_in[7];
    const float* b2    = (const float*)d_in[8];
    const float* W3    = (const float*)d_in[9];
    const float* b3    = (const float*)d_in[10];
    const float* W4    = (const float*)d_in[11];
    const float* b4    = (const float*)d_in[12];
    float* out = (float*)d_out;

    const size_t ftBytes = (size_t)NB * NPIX * FDIM * sizeof(_Float16);

    if (ws_size >= FT_BYTE_OFF + ftBytes) {
        _Float16* wf = (_Float16*)d_ws;
        _Float16* ft = (_Float16*)((char*)d_ws + FT_BYTE_OFF);
        prep_kernel<<<TR16_BLOCKS + 12, 256, 0, stream>>>(feats, W1, W2, W3, wf);
        decoder_mfma3<<<NB * NPTS / 128, 256, 0, stream>>>(ft, pts, k, rt, Bg, wf,
                                                           b1, b2, b3, W4, b4, out);
    } else {
        decoder_valu<<<NB * NPTS / 64, 64, 0, stream>>>(feats, pts, k, rt, Bg,
                                                        W1, b1, W2, b2, W3, b3, W4, b4, out);
    }
}